// Round 1
// baseline (867.277 us; speedup 1.0000x reference)
//
#include <hip/hip_runtime.h>
#include <math.h>

#define V_N 100000
#define KNN 64
#define OUTW 448   // 3*128 + 64

// out[v][j] = relu(sum_i in[v][i] * W[i][j] + b[j]),  j in [0,64)
// 256 threads = 4 rows/block, W staged in LDS.
template<int IN>
__global__ __launch_bounds__(256) void dense_kernel(
    const float* __restrict__ in, int in_stride,
    const float* __restrict__ W, const float* __restrict__ b,
    float* __restrict__ out, int out_stride)
{
    __shared__ float sW[IN * 64];
    __shared__ float sIn[4][IN];
    const int tid = threadIdx.x;

    for (int i = tid; i < IN * 64; i += 256) sW[i] = W[i];

    const int r = tid >> 6;       // row within block
    const int j = tid & 63;       // output feature
    const int v = blockIdx.x * 4 + r;

    for (int i = tid; i < 4 * IN; i += 256) {
        int rr = i / IN, cc = i % IN;
        int vv = blockIdx.x * 4 + rr;
        sIn[rr][cc] = (vv < V_N) ? in[(size_t)vv * in_stride + cc] : 0.f;
    }
    __syncthreads();
    if (v >= V_N) return;

    float acc = b[j];
#pragma unroll
    for (int i = 0; i < IN; ++i)
        acc = fmaf(sIn[r][i], sW[i * 64 + j], acc);

    out[(size_t)v * out_stride + j] = fmaxf(acc, 0.f);
}

// One wave per row v. lane = feature. For each of 64 neighbors:
//   val = exp(-10*dsq[v][k]) * feats[idx[v][k]][lane]
// out[v][off+lane]    = mean_k val - feats[v][lane]
// out[v][off+64+lane] = max_k  val - feats[v][lane]
__global__ __launch_bounds__(256) void acc_kernel(
    const float* __restrict__ dsq,
    const int*   __restrict__ idx,
    const float* __restrict__ feats, int fstride,
    float* __restrict__ out, int col_off)
{
    const int wid  = threadIdx.x >> 6;
    const int lane = threadIdx.x & 63;
    const int v = blockIdx.x * 4 + wid;
    if (v >= V_N) return;

    const float wl = __expf(-10.f * dsq[(size_t)v * KNN + lane]);
    const int   il = idx[(size_t)v * KNN + lane] * fstride;  // pre-scaled row base

    float sum = 0.f;
    float mx  = 0.f;   // vals are >= 0 (relu feats * positive weight)
#pragma unroll 8
    for (int k = 0; k < KNN; ++k) {
        const float wk   = __shfl(wl, k);
        const int   base = __shfl(il, k);
        const float val  = wk * feats[(size_t)base + lane];
        sum += val;
        mx   = fmaxf(mx, val);
    }

    const float self = feats[(size_t)v * fstride + lane];
    out[(size_t)v * OUTW + col_off + lane]      = sum * (1.f / 64.f) - self;
    out[(size_t)v * OUTW + col_off + 64 + lane] = mx - self;
}

__global__ __launch_bounds__(256) void copyx_kernel(
    const float* __restrict__ x, float* __restrict__ out)
{
    int t = blockIdx.x * blockDim.x + threadIdx.x;
    if (t < V_N * 64) {
        int v = t >> 6, f = t & 63;
        out[(size_t)v * OUTW + 384 + f] = x[t];
    }
}

extern "C" void kernel_launch(void* const* d_in, const int* in_sizes, int n_in,
                              void* d_out, int out_size, void* d_ws, size_t ws_size,
                              hipStream_t stream)
{
    const float* x   = (const float*)d_in[0];
    const float* dsq = (const float*)d_in[1];
    const int*   idx = (const int*)  d_in[2];
    const float* W0  = (const float*)d_in[3];
    const float* b0  = (const float*)d_in[4];
    const float* W1  = (const float*)d_in[5];
    const float* b1  = (const float*)d_in[6];
    const float* W2  = (const float*)d_in[7];
    const float* b2  = (const float*)d_in[8];
    float* out = (float*)d_out;

    // feats scratch lives in out cols [384,448) (stride OUTW); overwritten by
    // copyx_kernel at the end. No d_ws dependence.
    float* feats = out + 384;

    const dim3 blk(256);
    const int nb = (V_N + 3) / 4;

    // layer 0
    dense_kernel<64><<<nb, blk, 0, stream>>>(x, 64, W0, b0, feats, OUTW);
    acc_kernel<<<nb, blk, 0, stream>>>(dsq, idx, feats, OUTW, out, 0);
    // layer 1 (input = f0 = out cols [0,128))
    dense_kernel<128><<<nb, blk, 0, stream>>>(out + 0, OUTW, W1, b1, feats, OUTW);
    acc_kernel<<<nb, blk, 0, stream>>>(dsq, idx, feats, OUTW, out, 128);
    // layer 2 (input = f1 = out cols [128,256))
    dense_kernel<128><<<nb, blk, 0, stream>>>(out + 128, OUTW, W2, b2, feats, OUTW);
    acc_kernel<<<nb, blk, 0, stream>>>(dsq, idx, feats, OUTW, out, 256);
    // final: overwrite scratch region with x
    copyx_kernel<<<(V_N * 64 + 255) / 256, blk, 0, stream>>>(x, out);
}

// Round 2
// 558.395 us; speedup vs baseline: 1.5532x; 1.5532x over previous
//
#include <hip/hip_runtime.h>
#include <hip/hip_bf16.h>
#include <math.h>

#define V_N   100000
#define KNN   64
#define OUTW  448           // 3*128 + 64 output cols (f32)
#define ROWB  1792          // OUTW*4 bytes per out row
#define TBLOFF 1536         // byte offset of bf16 feats table inside out row (col 384)

// ---------------------------------------------------------------------------
// dense2: out-of-place dense + ReLU, writing the result as a bf16 table
// embedded in the out buffer at byte offset TBLOFF of each row.
// Block = 256 threads computes a 64-row x 64-col tile, register 4x4 per thread.
// ---------------------------------------------------------------------------
template<int IN>
__global__ __launch_bounds__(256) void dense2_kernel(
    const float* __restrict__ in, int in_stride,
    const float* __restrict__ W, const float* __restrict__ b,
    char* __restrict__ outbase)
{
    __shared__ float sAT[IN][68];      // transposed in-tile, padded (16B-aligned rows)
    __shared__ float sW[IN * 64];      // W row-major [i][c]

    const int tid = threadIdx.x;
    const int v0  = blockIdx.x * 64;

    // stage in-tile transposed: sAT[i][r] = in[v0+r][i]
#pragma unroll
    for (int e = tid; e < 64 * IN; e += 256) {
        const int r = e / IN, i = e % IN;
        const int v = v0 + r;
        sAT[i][r] = (v < V_N) ? in[(size_t)v * in_stride + i] : 0.f;
    }
    // stage W
#pragma unroll
    for (int e = tid; e < IN * 64; e += 256) sW[e] = W[e];
    __syncthreads();

    const int r0 = (tid >> 4) * 4;     // 16 row-groups of 4
    const int c0 = (tid & 15) * 4;     // 16 col-groups of 4

    float acc[4][4];
#pragma unroll
    for (int ri = 0; ri < 4; ++ri)
#pragma unroll
        for (int ci = 0; ci < 4; ++ci) acc[ri][ci] = b[c0 + ci];

#pragma unroll 4
    for (int i = 0; i < IN; ++i) {
        const float4 av = *(const float4*)&sAT[i][r0];
        const float4 wv = *(const float4*)&sW[i * 64 + c0];
        const float a[4] = {av.x, av.y, av.z, av.w};
        const float w[4] = {wv.x, wv.y, wv.z, wv.w};
#pragma unroll
        for (int ri = 0; ri < 4; ++ri)
#pragma unroll
            for (int ci = 0; ci < 4; ++ci)
                acc[ri][ci] = fmaf(a[ri], w[ci], acc[ri][ci]);
    }

    // epilogue: relu -> bf16, 4 cols per row packed as ushort4 (8B store)
#pragma unroll
    for (int ri = 0; ri < 4; ++ri) {
        const int v = v0 + r0 + ri;
        if (v >= V_N) continue;
        ushort4 pk;
        __hip_bfloat16 h0 = __float2bfloat16(fmaxf(acc[ri][0], 0.f));
        __hip_bfloat16 h1 = __float2bfloat16(fmaxf(acc[ri][1], 0.f));
        __hip_bfloat16 h2 = __float2bfloat16(fmaxf(acc[ri][2], 0.f));
        __hip_bfloat16 h3 = __float2bfloat16(fmaxf(acc[ri][3], 0.f));
        pk.x = *(unsigned short*)&h0; pk.y = *(unsigned short*)&h1;
        pk.z = *(unsigned short*)&h2; pk.w = *(unsigned short*)&h3;
        *(ushort4*)(outbase + (size_t)v * ROWB + TBLOFF + c0 * 2) = pk;
    }
}

// ---------------------------------------------------------------------------
// acc2: one wave per row v; lane = feature. Gathers 64 bf16 rows (128B each,
// one cache line), accumulates mean & max in f32, subtracts self, writes f32.
// ---------------------------------------------------------------------------
__global__ __launch_bounds__(256) void acc2_kernel(
    const float* __restrict__ dsq,
    const int*   __restrict__ idx,
    const char*  __restrict__ tbl,      // = (char*)out, bf16 rows at TBLOFF
    float* __restrict__ out, int col_off)
{
    const int wid  = threadIdx.x >> 6;
    const int lane = threadIdx.x & 63;
    const int v = blockIdx.x * 4 + wid;
    if (v >= V_N) return;

    const float wl = __expf(-10.f * dsq[(size_t)v * KNN + lane]);
    const int   il = idx[(size_t)v * KNN + lane] * ROWB + TBLOFF; // byte base

    float sum = 0.f;
    float mx  = 0.f;   // vals >= 0 (relu feats, positive weights)
#pragma unroll 16
    for (int k = 0; k < KNN; ++k) {
        const float wk   = __shfl(wl, k);
        const int   base = __shfl(il, k);
        const __hip_bfloat16* row = (const __hip_bfloat16*)(tbl + base);
        const float val = wk * __bfloat162float(row[lane]);
        sum += val;
        mx   = fmaxf(mx, val);
    }

    const __hip_bfloat16* selfrow =
        (const __hip_bfloat16*)(tbl + (size_t)v * ROWB + TBLOFF);
    const float self = __bfloat162float(selfrow[lane]);

    out[(size_t)v * OUTW + col_off + lane]      = sum * (1.f / 64.f) - self;
    out[(size_t)v * OUTW + col_off + 64 + lane] = mx - self;
}

// ---------------------------------------------------------------------------
// copyx: overwrite the table region (cols 384..448) with x, float4-vectorized.
// ---------------------------------------------------------------------------
__global__ __launch_bounds__(256) void copyx_kernel(
    const float* __restrict__ x, float* __restrict__ out)
{
    const int t = blockIdx.x * blockDim.x + threadIdx.x;
    if (t < V_N * 16) {
        const int v = t >> 4, f4 = (t & 15) * 4;
        *(float4*)&out[(size_t)v * OUTW + 384 + f4] =
            *(const float4*)&x[(size_t)v * 64 + f4];
    }
}

extern "C" void kernel_launch(void* const* d_in, const int* in_sizes, int n_in,
                              void* d_out, int out_size, void* d_ws, size_t ws_size,
                              hipStream_t stream)
{
    const float* x   = (const float*)d_in[0];
    const float* dsq = (const float*)d_in[1];
    const int*   idx = (const int*)  d_in[2];
    const float* W0  = (const float*)d_in[3];
    const float* b0  = (const float*)d_in[4];
    const float* W1  = (const float*)d_in[5];
    const float* b1  = (const float*)d_in[6];
    const float* W2  = (const float*)d_in[7];
    const float* b2  = (const float*)d_in[8];
    float* out = (float*)d_out;
    char*  outc = (char*)d_out;

    const dim3 blk(256);
    const int nb_dense = (V_N + 63) / 64;   // 1563
    const int nb_acc   = (V_N + 3) / 4;     // 25000

    // layer 0: feats = relu(x @ W0 + b0) -> bf16 table
    dense2_kernel<64><<<nb_dense, blk, 0, stream>>>(x, 64, W0, b0, outc);
    acc2_kernel<<<nb_acc, blk, 0, stream>>>(dsq, idx, outc, out, 0);
    // layer 1: in = f0 = out cols [0,128)
    dense2_kernel<128><<<nb_dense, blk, 0, stream>>>(out + 0, OUTW, W1, b1, outc);
    acc2_kernel<<<nb_acc, blk, 0, stream>>>(dsq, idx, outc, out, 128);
    // layer 2: in = f1 = out cols [128,256)
    dense2_kernel<128><<<nb_dense, blk, 0, stream>>>(out + 128, OUTW, W2, b2, outc);
    acc2_kernel<<<nb_acc, blk, 0, stream>>>(dsq, idx, outc, out, 256);
    // overwrite table region with x
    copyx_kernel<<<(V_N * 16 + 255) / 256, blk, 0, stream>>>(x, out);
}

// Round 3
// 459.479 us; speedup vs baseline: 1.8875x; 1.2153x over previous
//
#include <hip/hip_runtime.h>
#include <hip/hip_bf16.h>
#include <math.h>

#define V_N   100000
#define KNN   64
#define OUTW  448           // 3*128 + 64 output cols (f32)
#define ROWB  1792          // OUTW*4 bytes per out row
#define TBLOFF 1536         // byte offset of bf16 feats table inside out row (col 384)

// ---------------------------------------------------------------------------
// dense2: out-of-place dense + ReLU, writing the result as a bf16 table
// embedded in the out buffer at byte offset TBLOFF of each row.
// Block = 256 threads computes a 64-row x 64-col tile, register 4x4 per thread.
// ---------------------------------------------------------------------------
template<int IN>
__global__ __launch_bounds__(256) void dense2_kernel(
    const float* __restrict__ in, int in_stride,
    const float* __restrict__ W, const float* __restrict__ b,
    char* __restrict__ outbase)
{
    __shared__ float sAT[IN][68];      // transposed in-tile, padded
    __shared__ float sW[IN * 64];      // W row-major [i][c]

    const int tid = threadIdx.x;
    const int v0  = blockIdx.x * 64;

#pragma unroll
    for (int e = tid; e < 64 * IN; e += 256) {
        const int r = e / IN, i = e % IN;
        const int v = v0 + r;
        sAT[i][r] = (v < V_N) ? in[(size_t)v * in_stride + i] : 0.f;
    }
#pragma unroll
    for (int e = tid; e < IN * 64; e += 256) sW[e] = W[e];
    __syncthreads();

    const int r0 = (tid >> 4) * 4;
    const int c0 = (tid & 15) * 4;

    float acc[4][4];
#pragma unroll
    for (int ri = 0; ri < 4; ++ri)
#pragma unroll
        for (int ci = 0; ci < 4; ++ci) acc[ri][ci] = b[c0 + ci];

#pragma unroll 4
    for (int i = 0; i < IN; ++i) {
        const float4 av = *(const float4*)&sAT[i][r0];
        const float4 wv = *(const float4*)&sW[i * 64 + c0];
        const float a[4] = {av.x, av.y, av.z, av.w};
        const float w[4] = {wv.x, wv.y, wv.z, wv.w};
#pragma unroll
        for (int ri = 0; ri < 4; ++ri)
#pragma unroll
            for (int ci = 0; ci < 4; ++ci)
                acc[ri][ci] = fmaf(a[ri], w[ci], acc[ri][ci]);
    }

#pragma unroll
    for (int ri = 0; ri < 4; ++ri) {
        const int v = v0 + r0 + ri;
        if (v >= V_N) continue;
        ushort4 pk;
        __hip_bfloat16 h0 = __float2bfloat16(fmaxf(acc[ri][0], 0.f));
        __hip_bfloat16 h1 = __float2bfloat16(fmaxf(acc[ri][1], 0.f));
        __hip_bfloat16 h2 = __float2bfloat16(fmaxf(acc[ri][2], 0.f));
        __hip_bfloat16 h3 = __float2bfloat16(fmaxf(acc[ri][3], 0.f));
        pk.x = *(unsigned short*)&h0; pk.y = *(unsigned short*)&h1;
        pk.z = *(unsigned short*)&h2; pk.w = *(unsigned short*)&h3;
        *(ushort4*)(outbase + (size_t)v * ROWB + TBLOFF + c0 * 2) = pk;
    }
}

// ---------------------------------------------------------------------------
// acc3: one wave per row v. 4 neighbor rows gathered per iteration:
//   lane group g = lane>>4 takes neighbor it*4+g,
//   lane handles features fq*4..fq*4+3 (fq = lane&15) via one 8B load.
// (w, rowbase) pairs staged in LDS -> 1 ds_read_b64 per iter (broadcast).
// Epilogue: shfl_xor reduce over the 4 groups, float4 stores.
// Grid covers V_N exactly (25000 blocks x 4 waves).
// ---------------------------------------------------------------------------
__global__ __launch_bounds__(256) void acc3_kernel(
    const float* __restrict__ dsq,
    const int*   __restrict__ idx,
    const char*  __restrict__ tbl,
    float* __restrict__ out, int col_off)
{
    __shared__ float2 pairs[4][64];
    const int tid  = threadIdx.x;
    const int wid  = tid >> 6;
    const int lane = tid & 63;
    const int v    = blockIdx.x * 4 + wid;

    const float d  = dsq[(size_t)v * KNN + lane];
    const int   ib = idx[(size_t)v * KNN + lane] * ROWB + TBLOFF;  // byte base
    const float w  = __expf(-10.f * d);
    pairs[wid][lane] = make_float2(w, __int_as_float(ib));
    __syncthreads();

    const int g  = lane >> 4;
    const int fq = lane & 15;
    const char* ftbl = tbl + fq * 8;

    float s0=0.f,s1=0.f,s2=0.f,s3=0.f;
    float m0=0.f,m1=0.f,m2=0.f,m3=0.f;   // vals >= 0 (relu feats, pos weights)
#pragma unroll
    for (int it = 0; it < 16; ++it) {
        const float2 pw = pairs[wid][it * 4 + g];
        const float wk = pw.x;
        const int   bk = __float_as_int(pw.y);
        const uint2 pk = *(const uint2*)(ftbl + bk);
        const float f0 = __uint_as_float(pk.x << 16);
        const float f1 = __uint_as_float(pk.x & 0xffff0000u);
        const float f2 = __uint_as_float(pk.y << 16);
        const float f3 = __uint_as_float(pk.y & 0xffff0000u);
        const float v0 = wk * f0, v1 = wk * f1, v2 = wk * f2, v3 = wk * f3;
        s0 += v0; s1 += v1; s2 += v2; s3 += v3;
        m0 = fmaxf(m0, v0); m1 = fmaxf(m1, v1);
        m2 = fmaxf(m2, v2); m3 = fmaxf(m3, v3);
    }

    // reduce across the 4 neighbor groups (lane bits 4,5)
    s0 += __shfl_xor(s0, 16); s1 += __shfl_xor(s1, 16);
    s2 += __shfl_xor(s2, 16); s3 += __shfl_xor(s3, 16);
    m0 = fmaxf(m0, __shfl_xor(m0, 16)); m1 = fmaxf(m1, __shfl_xor(m1, 16));
    m2 = fmaxf(m2, __shfl_xor(m2, 16)); m3 = fmaxf(m3, __shfl_xor(m3, 16));
    s0 += __shfl_xor(s0, 32); s1 += __shfl_xor(s1, 32);
    s2 += __shfl_xor(s2, 32); s3 += __shfl_xor(s3, 32);
    m0 = fmaxf(m0, __shfl_xor(m0, 32)); m1 = fmaxf(m1, __shfl_xor(m1, 32));
    m2 = fmaxf(m2, __shfl_xor(m2, 32)); m3 = fmaxf(m3, __shfl_xor(m3, 32));

    if (g < 2) {
        const uint2 sp = *(const uint2*)(tbl + (size_t)v * ROWB + TBLOFF + fq * 8);
        const float e0 = __uint_as_float(sp.x << 16);
        const float e1 = __uint_as_float(sp.x & 0xffff0000u);
        const float e2 = __uint_as_float(sp.y << 16);
        const float e3 = __uint_as_float(sp.y & 0xffff0000u);
        if (g == 0) {
            const float4 r = make_float4(s0 * (1.f/64.f) - e0, s1 * (1.f/64.f) - e1,
                                         s2 * (1.f/64.f) - e2, s3 * (1.f/64.f) - e3);
            *(float4*)&out[(size_t)v * OUTW + col_off + fq * 4] = r;
        } else {
            const float4 r = make_float4(m0 - e0, m1 - e1, m2 - e2, m3 - e3);
            *(float4*)&out[(size_t)v * OUTW + col_off + 64 + fq * 4] = r;
        }
    }
}

// ---------------------------------------------------------------------------
// copyx: overwrite the table region (cols 384..448) with x, float4-vectorized.
// ---------------------------------------------------------------------------
__global__ __launch_bounds__(256) void copyx_kernel(
    const float* __restrict__ x, float* __restrict__ out)
{
    const int t = blockIdx.x * blockDim.x + threadIdx.x;
    if (t < V_N * 16) {
        const int v = t >> 4, f4 = (t & 15) * 4;
        *(float4*)&out[(size_t)v * OUTW + 384 + f4] =
            *(const float4*)&x[(size_t)v * 64 + f4];
    }
}

extern "C" void kernel_launch(void* const* d_in, const int* in_sizes, int n_in,
                              void* d_out, int out_size, void* d_ws, size_t ws_size,
                              hipStream_t stream)
{
    const float* x   = (const float*)d_in[0];
    const float* dsq = (const float*)d_in[1];
    const int*   idx = (const int*)  d_in[2];
    const float* W0  = (const float*)d_in[3];
    const float* b0  = (const float*)d_in[4];
    const float* W1  = (const float*)d_in[5];
    const float* b1  = (const float*)d_in[6];
    const float* W2  = (const float*)d_in[7];
    const float* b2  = (const float*)d_in[8];
    float* out = (float*)d_out;
    char*  outc = (char*)d_out;

    const dim3 blk(256);
    const int nb_dense = (V_N + 63) / 64;   // 1563
    const int nb_acc   = V_N / 4;           // 25000 (exact)

    dense2_kernel<64><<<nb_dense, blk, 0, stream>>>(x, 64, W0, b0, outc);
    acc3_kernel<<<nb_acc, blk, 0, stream>>>(dsq, idx, outc, out, 0);
    dense2_kernel<128><<<nb_dense, blk, 0, stream>>>(out + 0, OUTW, W1, b1, outc);
    acc3_kernel<<<nb_acc, blk, 0, stream>>>(dsq, idx, outc, out, 128);
    dense2_kernel<128><<<nb_dense, blk, 0, stream>>>(out + 128, OUTW, W2, b2, outc);
    acc3_kernel<<<nb_acc, blk, 0, stream>>>(dsq, idx, outc, out, 256);
    copyx_kernel<<<(V_N * 16 + 255) / 256, blk, 0, stream>>>(x, out);
}

// Round 4
// 361.334 us; speedup vs baseline: 2.4002x; 1.2716x over previous
//
#include <hip/hip_runtime.h>
#include <hip/hip_bf16.h>
#include <math.h>

#define V_N   100000
#define KNN   64
#define OUTW  448           // 3*128 + 64 output cols (f32)
#define ROWB  1792          // OUTW*4 bytes per out row
#define TBLOFF 1536         // byte offset of bf16 feats table inside out row (col 384)

typedef __attribute__((ext_vector_type(8))) short bf16x8;
typedef __attribute__((ext_vector_type(4))) float f32x4;

__device__ __forceinline__ unsigned short bf16bits(float f) {
    __hip_bfloat16 h = __float2bfloat16(f);
    return *(unsigned short*)&h;
}

// ---------------------------------------------------------------------------
// dense_mfma: feats = relu(in @ W + b) -> bf16 table at TBLOFF of each out row.
// Block = 256 threads = 4 waves; each wave does a 16-row x 64-col tile via
// mfma_f32_16x16x32_bf16 (4 j-tiles x IN/32 k-steps).
// W (f32 [IN][64]) is staged transposed+bf16 into LDS [64][IN+8].
// A fragments are read f32 from global and converted inline.
// ---------------------------------------------------------------------------
template<int IN>
__global__ __launch_bounds__(256) void dense_mfma_kernel(
    const float* __restrict__ in, int in_stride,
    const float* __restrict__ W, const float* __restrict__ b,
    char* __restrict__ outbase)
{
    __shared__ __hip_bfloat16 sWt[64][IN + 8];

    const int tid = threadIdx.x;
    const int v0  = blockIdx.x * 64;

    // stage W transposed: sWt[j][k] = bf16(W[k][j])
#pragma unroll
    for (int e = tid; e < IN * 64; e += 256) {
        const int k = e >> 6, j = e & 63;
        sWt[j][k] = __float2bfloat16(W[e]);
    }
    __syncthreads();

    const int wv   = tid >> 6;
    const int lane = tid & 63;
    const int r    = lane & 15;          // A row within tile / B,D col
    const int ko   = (lane >> 4) * 8;    // k sub-offset within 32-block

    const int arow_v = min(v0 + wv * 16 + r, V_N - 1);
    const float* arow = in + (size_t)arow_v * in_stride;

    f32x4 acc[4];
#pragma unroll
    for (int t = 0; t < 4; ++t) {
        const float bb = b[t * 16 + r];
        acc[t] = (f32x4){bb, bb, bb, bb};
    }

#pragma unroll
    for (int kb = 0; kb < IN / 32; ++kb) {
        const float4 a0 = *(const float4*)(arow + kb * 32 + ko);
        const float4 a1 = *(const float4*)(arow + kb * 32 + ko + 4);
        const float av[8] = {a0.x, a0.y, a0.z, a0.w, a1.x, a1.y, a1.z, a1.w};
        bf16x8 af;
#pragma unroll
        for (int e = 0; e < 8; ++e) af[e] = (short)bf16bits(av[e]);

#pragma unroll
        for (int t = 0; t < 4; ++t) {
            const bf16x8 bfr = *(const bf16x8*)&sWt[t * 16 + r][kb * 32 + ko];
            acc[t] = __builtin_amdgcn_mfma_f32_16x16x32_bf16(af, bfr, acc[t], 0, 0, 0);
        }
    }

    // epilogue: relu -> bf16 table. D: col = lane&15, row = (lane>>4)*4 + reg
#pragma unroll
    for (int t = 0; t < 4; ++t) {
#pragma unroll
        for (int reg = 0; reg < 4; ++reg) {
            const int orow = v0 + wv * 16 + (lane >> 4) * 4 + reg;
            if (orow < V_N) {
                const int j = t * 16 + r;
                *(unsigned short*)(outbase + (size_t)orow * ROWB + TBLOFF + j * 2) =
                    bf16bits(fmaxf(acc[t][reg], 0.f));
            }
        }
    }
}

// ---------------------------------------------------------------------------
// acc4: one wave per row v. 8 neighbor rows gathered per iteration:
//   lane group g = lane>>3 takes neighbor it*8+g,
//   lane handles features fq*8..fq*8+7 (fq = lane&7) via one 16B load
//   (8 lanes x 16B = one 128B row = one cache line).
// (w, rowbase) pairs staged in LDS -> 1 conflict-free ds_read_b64 per iter.
// Epilogue: 3-level shfl_xor butterfly, lanes 0-7 store mean, 8-15 store max.
// ---------------------------------------------------------------------------
__global__ __launch_bounds__(256) void acc4_kernel(
    const float* __restrict__ dsq,
    const int*   __restrict__ idx,
    const char*  __restrict__ tbl,
    float* __restrict__ out, int col_off)
{
    __shared__ float2 pairs[4][64];
    const int tid  = threadIdx.x;
    const int wid  = tid >> 6;
    const int lane = tid & 63;
    const int v    = blockIdx.x * 4 + wid;

    const float d  = dsq[(size_t)v * KNN + lane];
    const int   ib = idx[(size_t)v * KNN + lane] * ROWB + TBLOFF;
    pairs[wid][lane] = make_float2(__expf(-10.f * d), __int_as_float(ib));
    __syncthreads();

    const int g  = lane >> 3;
    const int fq = lane & 7;
    const unsigned foff = fq * 16;

    float s[8] = {0.f, 0.f, 0.f, 0.f, 0.f, 0.f, 0.f, 0.f};
    float m[8] = {0.f, 0.f, 0.f, 0.f, 0.f, 0.f, 0.f, 0.f};
#pragma unroll
    for (int it = 0; it < 8; ++it) {
        const float2 pw = pairs[wid][it * 8 + g];
        const float wk = pw.x;
        const unsigned bk = (unsigned)__float_as_int(pw.y) + foff;
        const uint4 pk = *(const uint4*)(tbl + bk);
        const unsigned u[4] = {pk.x, pk.y, pk.z, pk.w};
#pragma unroll
        for (int q = 0; q < 4; ++q) {
            const float flo = __uint_as_float(u[q] << 16);
            const float fhi = __uint_as_float(u[q] & 0xffff0000u);
            const float vlo = wk * flo, vhi = wk * fhi;
            s[2 * q]     += vlo;  s[2 * q + 1] += vhi;
            m[2 * q]     = fmaxf(m[2 * q], vlo);
            m[2 * q + 1] = fmaxf(m[2 * q + 1], vhi);
        }
    }

    // butterfly over the 8 neighbor groups (lane bits 3,4,5)
#pragma unroll
    for (int msk = 8; msk <= 32; msk <<= 1) {
#pragma unroll
        for (int e = 0; e < 8; ++e) {
            s[e] += __shfl_xor(s[e], msk);
            m[e] = fmaxf(m[e], __shfl_xor(m[e], msk));
        }
    }

    if (g < 2) {
        const uint4 sp = *(const uint4*)(tbl + (size_t)v * ROWB + TBLOFF + foff);
        const unsigned su[4] = {sp.x, sp.y, sp.z, sp.w};
        float e[8];
#pragma unroll
        for (int q = 0; q < 4; ++q) {
            e[2 * q]     = __uint_as_float(su[q] << 16);
            e[2 * q + 1] = __uint_as_float(su[q] & 0xffff0000u);
        }
        float* dst;
        float r[8];
        if (g == 0) {
#pragma unroll
            for (int k = 0; k < 8; ++k) r[k] = s[k] * (1.f / 64.f) - e[k];
            dst = &out[(size_t)v * OUTW + col_off + fq * 8];
        } else {
#pragma unroll
            for (int k = 0; k < 8; ++k) r[k] = m[k] - e[k];
            dst = &out[(size_t)v * OUTW + col_off + 64 + fq * 8];
        }
        *(float4*)dst       = make_float4(r[0], r[1], r[2], r[3]);
        *(float4*)(dst + 4) = make_float4(r[4], r[5], r[6], r[7]);
    }
}

// ---------------------------------------------------------------------------
// copyx: overwrite the table region (cols 384..448) with x, float4-vectorized.
// ---------------------------------------------------------------------------
__global__ __launch_bounds__(256) void copyx_kernel(
    const float* __restrict__ x, float* __restrict__ out)
{
    const int t = blockIdx.x * blockDim.x + threadIdx.x;
    if (t < V_N * 16) {
        const int v = t >> 4, f4 = (t & 15) * 4;
        *(float4*)&out[(size_t)v * OUTW + 384 + f4] =
            *(const float4*)&x[(size_t)v * 64 + f4];
    }
}

extern "C" void kernel_launch(void* const* d_in, const int* in_sizes, int n_in,
                              void* d_out, int out_size, void* d_ws, size_t ws_size,
                              hipStream_t stream)
{
    const float* x   = (const float*)d_in[0];
    const float* dsq = (const float*)d_in[1];
    const int*   idx = (const int*)  d_in[2];
    const float* W0  = (const float*)d_in[3];
    const float* b0  = (const float*)d_in[4];
    const float* W1  = (const float*)d_in[5];
    const float* b1  = (const float*)d_in[6];
    const float* W2  = (const float*)d_in[7];
    const float* b2  = (const float*)d_in[8];
    float* out = (float*)d_out;
    char*  outc = (char*)d_out;

    const dim3 blk(256);
    const int nb_dense = (V_N + 63) / 64;   // 1563
    const int nb_acc   = V_N / 4;           // 25000 (exact)

    dense_mfma_kernel<64><<<nb_dense, blk, 0, stream>>>(x, 64, W0, b0, outc);
    acc4_kernel<<<nb_acc, blk, 0, stream>>>(dsq, idx, outc, out, 0);
    dense_mfma_kernel<128><<<nb_dense, blk, 0, stream>>>(out + 0, OUTW, W1, b1, outc);
    acc4_kernel<<<nb_acc, blk, 0, stream>>>(dsq, idx, outc, out, 128);
    dense_mfma_kernel<128><<<nb_dense, blk, 0, stream>>>(out + 128, OUTW, W2, b2, outc);
    acc4_kernel<<<nb_acc, blk, 0, stream>>>(dsq, idx, outc, out, 256);
    copyx_kernel<<<(V_N * 16 + 255) / 256, blk, 0, stream>>>(x, out);
}

// Round 5
// 359.948 us; speedup vs baseline: 2.4095x; 1.0039x over previous
//
#include <hip/hip_runtime.h>
#include <hip/hip_bf16.h>
#include <math.h>

#define V_N   100000
#define KNN   64
#define OUTW  448           // 3*128 + 64 output cols (f32)
#define ROWB  1792          // OUTW*4 bytes per out row
#define TBLOFF 1536         // byte offset of bf16 feats table inside out row (col 384)

typedef __attribute__((ext_vector_type(8))) short bf16x8;
typedef __attribute__((ext_vector_type(4))) float f32x4;

__device__ __forceinline__ unsigned short bf16bits(float f) {
    __hip_bfloat16 h = __float2bfloat16(f);
    return *(unsigned short*)&h;
}

// ---------------------------------------------------------------------------
// dense_mfma: feats = relu(in @ W + b) -> bf16 table at TBLOFF of each out row.
// Block = 256 threads = 4 waves; each wave does a 16-row x 64-col tile via
// mfma_f32_16x16x32_bf16.
// ---------------------------------------------------------------------------
template<int IN>
__global__ __launch_bounds__(256) void dense_mfma_kernel(
    const float* __restrict__ in, int in_stride,
    const float* __restrict__ W, const float* __restrict__ b,
    char* __restrict__ outbase)
{
    __shared__ __hip_bfloat16 sWt[64][IN + 8];

    const int tid = threadIdx.x;
    const int v0  = blockIdx.x * 64;

#pragma unroll
    for (int e = tid; e < IN * 64; e += 256) {
        const int k = e >> 6, j = e & 63;
        sWt[j][k] = __float2bfloat16(W[e]);
    }
    __syncthreads();

    const int wv   = tid >> 6;
    const int lane = tid & 63;
    const int r    = lane & 15;
    const int ko   = (lane >> 4) * 8;

    const int arow_v = min(v0 + wv * 16 + r, V_N - 1);
    const float* arow = in + (size_t)arow_v * in_stride;

    f32x4 acc[4];
#pragma unroll
    for (int t = 0; t < 4; ++t) {
        const float bb = b[t * 16 + r];
        acc[t] = (f32x4){bb, bb, bb, bb};
    }

#pragma unroll
    for (int kb = 0; kb < IN / 32; ++kb) {
        const float4 a0 = *(const float4*)(arow + kb * 32 + ko);
        const float4 a1 = *(const float4*)(arow + kb * 32 + ko + 4);
        const float av[8] = {a0.x, a0.y, a0.z, a0.w, a1.x, a1.y, a1.z, a1.w};
        bf16x8 af;
#pragma unroll
        for (int e = 0; e < 8; ++e) af[e] = (short)bf16bits(av[e]);

#pragma unroll
        for (int t = 0; t < 4; ++t) {
            const bf16x8 bfr = *(const bf16x8*)&sWt[t * 16 + r][kb * 32 + ko];
            acc[t] = __builtin_amdgcn_mfma_f32_16x16x32_bf16(af, bfr, acc[t], 0, 0, 0);
        }
    }

#pragma unroll
    for (int t = 0; t < 4; ++t) {
#pragma unroll
        for (int reg = 0; reg < 4; ++reg) {
            const int orow = v0 + wv * 16 + (lane >> 4) * 4 + reg;
            if (orow < V_N) {
                const int j = t * 16 + r;
                *(unsigned short*)(outbase + (size_t)orow * ROWB + TBLOFF + j * 2) =
                    bf16bits(fmaxf(acc[t][reg], 0.f));
            }
        }
    }
}

// ---------------------------------------------------------------------------
// acc5: one wave per row v, 8 rows gathered per "iteration" as in acc4, but
// restructured as explicit 2-phase software pipeline:
//   phase 1: read all 8 (w, base) pairs from LDS, ISSUE all 8 dwordx4 gathers
//            (+ the self row, exec-masked) into a register buffer
//   phase 2: pure-VALU unpack/accumulate, then 3-level butterfly + stores
// This keeps 8 gathers in flight per wave (vs ~2-3 when load and use are
// interleaved), attacking the measured latency-bound regime.
// ---------------------------------------------------------------------------
__global__ __launch_bounds__(256) void acc5_kernel(
    const float* __restrict__ dsq,
    const int*   __restrict__ idx,
    const char*  __restrict__ tbl,
    float* __restrict__ out, int col_off)
{
    __shared__ float2 pairs[4][64];
    const int tid  = threadIdx.x;
    const int wid  = tid >> 6;
    const int lane = tid & 63;
    const int v    = blockIdx.x * 4 + wid;

    const float d  = dsq[(size_t)v * KNN + lane];
    const int   ib = idx[(size_t)v * KNN + lane] * ROWB + TBLOFF;
    pairs[wid][lane] = make_float2(__expf(-10.f * d), __int_as_float(ib));
    __syncthreads();

    const int g  = lane >> 3;
    const int fq = lane & 7;
    const unsigned foff = fq * 16;

    // ---- phase 1: issue everything ----
    float wk[8];
    uint4 buf[8];
#pragma unroll
    for (int it = 0; it < 8; ++it) {
        const float2 pw = pairs[wid][it * 8 + g];
        wk[it] = pw.x;
        buf[it] = *(const uint4*)(tbl + (unsigned)__float_as_int(pw.y) + foff);
    }
    uint4 sp = make_uint4(0u, 0u, 0u, 0u);
    if (g < 2) sp = *(const uint4*)(tbl + (size_t)v * ROWB + TBLOFF + foff);

    // ---- phase 2: accumulate ----
    float s[8] = {0.f, 0.f, 0.f, 0.f, 0.f, 0.f, 0.f, 0.f};
    float m[8] = {0.f, 0.f, 0.f, 0.f, 0.f, 0.f, 0.f, 0.f};
#pragma unroll
    for (int it = 0; it < 8; ++it) {
        const unsigned u[4] = {buf[it].x, buf[it].y, buf[it].z, buf[it].w};
        const float w = wk[it];
#pragma unroll
        for (int q = 0; q < 4; ++q) {
            const float vlo = w * __uint_as_float(u[q] << 16);
            const float vhi = w * __uint_as_float(u[q] & 0xffff0000u);
            s[2 * q]     += vlo;  s[2 * q + 1] += vhi;
            m[2 * q]     = fmaxf(m[2 * q], vlo);
            m[2 * q + 1] = fmaxf(m[2 * q + 1], vhi);
        }
    }

    // butterfly over the 8 neighbor groups (lane bits 3,4,5)
#pragma unroll
    for (int msk = 8; msk <= 32; msk <<= 1) {
#pragma unroll
        for (int e = 0; e < 8; ++e) {
            s[e] += __shfl_xor(s[e], msk);
            m[e] = fmaxf(m[e], __shfl_xor(m[e], msk));
        }
    }

    if (g < 2) {
        const unsigned su[4] = {sp.x, sp.y, sp.z, sp.w};
        float e[8];
#pragma unroll
        for (int q = 0; q < 4; ++q) {
            e[2 * q]     = __uint_as_float(su[q] << 16);
            e[2 * q + 1] = __uint_as_float(su[q] & 0xffff0000u);
        }
        float* dst;
        float r[8];
        if (g == 0) {
#pragma unroll
            for (int k = 0; k < 8; ++k) r[k] = s[k] * (1.f / 64.f) - e[k];
            dst = &out[(size_t)v * OUTW + col_off + fq * 8];
        } else {
#pragma unroll
            for (int k = 0; k < 8; ++k) r[k] = m[k] - e[k];
            dst = &out[(size_t)v * OUTW + col_off + 64 + fq * 8];
        }
        *(float4*)dst       = make_float4(r[0], r[1], r[2], r[3]);
        *(float4*)(dst + 4) = make_float4(r[4], r[5], r[6], r[7]);
    }
}

// ---------------------------------------------------------------------------
// copyx: overwrite the table region (cols 384..448) with x, float4-vectorized.
// ---------------------------------------------------------------------------
__global__ __launch_bounds__(256) void copyx_kernel(
    const float* __restrict__ x, float* __restrict__ out)
{
    const int t = blockIdx.x * blockDim.x + threadIdx.x;
    if (t < V_N * 16) {
        const int v = t >> 4, f4 = (t & 15) * 4;
        *(float4*)&out[(size_t)v * OUTW + 384 + f4] =
            *(const float4*)&x[(size_t)v * 64 + f4];
    }
}

extern "C" void kernel_launch(void* const* d_in, const int* in_sizes, int n_in,
                              void* d_out, int out_size, void* d_ws, size_t ws_size,
                              hipStream_t stream)
{
    const float* x   = (const float*)d_in[0];
    const float* dsq = (const float*)d_in[1];
    const int*   idx = (const int*)  d_in[2];
    const float* W0  = (const float*)d_in[3];
    const float* b0  = (const float*)d_in[4];
    const float* W1  = (const float*)d_in[5];
    const float* b1  = (const float*)d_in[6];
    const float* W2  = (const float*)d_in[7];
    const float* b2  = (const float*)d_in[8];
    float* out = (float*)d_out;
    char*  outc = (char*)d_out;

    const dim3 blk(256);
    const int nb_dense = (V_N + 63) / 64;   // 1563
    const int nb_acc   = V_N / 4;           // 25000 (exact)

    dense_mfma_kernel<64><<<nb_dense, blk, 0, stream>>>(x, 64, W0, b0, outc);
    acc5_kernel<<<nb_acc, blk, 0, stream>>>(dsq, idx, outc, out, 0);
    dense_mfma_kernel<128><<<nb_dense, blk, 0, stream>>>(out + 0, OUTW, W1, b1, outc);
    acc5_kernel<<<nb_acc, blk, 0, stream>>>(dsq, idx, outc, out, 128);
    dense_mfma_kernel<128><<<nb_dense, blk, 0, stream>>>(out + 128, OUTW, W2, b2, outc);
    acc5_kernel<<<nb_acc, blk, 0, stream>>>(dsq, idx, outc, out, 256);
    copyx_kernel<<<(V_N * 16 + 255) / 256, blk, 0, stream>>>(x, out);
}